// Round 1
// baseline (545.921 us; speedup 1.0000x reference)
//
#include <hip/hip_runtime.h>

// LSS-FPN round 11: conv rebuilt around mfma_f32_32x32x16_bf16.
// Per-wave tile 64sp x 64co (M2xN2 fragments) -> 4 ds_read_b128 per 4 MFMAs
// per tap = 64 FLOP/LDS-byte (4x the 16x16x32 version). 128-thread blocks,
// tile 128sp x 64co, ci chunk 16, LDS row stride 24 shorts (48 B: bank-floor,
// conflict-free, 16B-aligned). 38.8 KB LDS -> 4 blocks/CU for barrier overlap.
// Tail (gemm1x1 / softmax2 / binning / gather) unchanged from R10.

#define FH_ 16
#define FW_ 44
#define SP_ 704
#define XSTR 960         // xt rows per image (incl. halo slack)
#define NIMG 6
#define CIN 512
#define DCH 112
#define CCTX 80
#define NXY 128
#define NVOX (NXY * NXY)
#define NPTS (NIMG * DCH * SP_)
#define CHUNK 64

#define WROWS 232        // LDS X window rows (128-px tile + 3x3 halo)
#define XP 24            // conv LDS row stride in shorts (48 B)
#define TPL 288          // conv tiles per layer: 6 sp-blk * 8 co-blk * 6 img
#define CIP 40           // legacy padded LDS k-stride (gemm1x1)

typedef unsigned short u16;
typedef __attribute__((ext_vector_type(8))) short bf16x8;
typedef __attribute__((ext_vector_type(4))) float f32x4;
typedef __attribute__((ext_vector_type(16))) float f32x16;

__device__ __forceinline__ float bf2f(u16 b) {
    union { unsigned u; float f; } v; v.u = ((unsigned)b) << 16; return v.f;
}
__device__ __forceinline__ u16 f2bf(float f) {
    union { float f; unsigned u; } v; v.f = f;
    unsigned r = v.u + 0x7fffu + ((v.u >> 16) & 1u);   // RTNE
    return (u16)(r >> 16);
}
__device__ __forceinline__ int spad_of(int s) {
    return (s / 44) * 46 + (s % 44) + 47;
}

// ---------------- zero fill ---------------------------------------------------
__global__ void zero_k(float4* __restrict__ p, long n4) {
    long i = (long)blockIdx.x * blockDim.x + threadIdx.x;
    if (i < n4) p[i] = make_float4(0.f, 0.f, 0.f, 0.f);
}

// ---------------- src fp32 [n][ci][704] -> xt bf16 [n][XSTR][512] -------------
__global__ void src_to_xt_k(const float* __restrict__ src, short* __restrict__ xt) {
    int e = blockIdx.x * 256 + threadIdx.x;
    if (e >= NIMG * SP_ * CIN) return;
    int ci = e & 511;
    int r = e >> 9;
    int s = r % SP_, n = r / SP_;
    float v = src[((size_t)n * CIN + ci) * SP_ + s];
    xt[((size_t)n * XSTR + spad_of(s)) * 512 + ci] = (short)f2bf(v);
}

// ---------------- weight convert: fp32 [co][ci][9] -> bf16 [t][co][ci] --------
__global__ void wsplit_k(const float* __restrict__ w, short* __restrict__ hi) {
    int e = blockIdx.x * 256 + threadIdx.x;
    if (e >= CIN * CIN) return;
    const float* wp = w + (size_t)e * 9;
#pragma unroll
    for (int t = 0; t < 9; ++t)
        hi[(size_t)t * (CIN * CIN) + e] = (short)f2bf(wp[t]);
}

// dual: converts two 3x3 weight tensors in one dispatch
__global__ void wsplit_dual_k(const float* __restrict__ w1, short* __restrict__ o1,
                              const float* __restrict__ w2, short* __restrict__ o2) {
    int i = blockIdx.x * 256 + threadIdx.x;
    if (i >= 2 * CIN * CIN) return;
    int e = i & (CIN * CIN - 1);
    const float* w = (i < CIN * CIN) ? w1 : w2;
    short* o = (i < CIN * CIN) ? o1 : o2;
    const float* wp = w + (size_t)e * 9;
#pragma unroll
    for (int t = 0; t < 9; ++t)
        o[(size_t)t * (CIN * CIN) + e] = (short)f2bf(wp[t]);
}

// dual 1x1 weights fp32 [co][ci] -> bf16
__global__ void wsplit1_dual_k(const float* __restrict__ wd, short* __restrict__ od,
                               const float* __restrict__ wc, short* __restrict__ oc) {
    int i = blockIdx.x * 256 + threadIdx.x;
    if (i < DCH * CIN) od[i] = (short)f2bf(wd[i]);
    else if (i < DCH * CIN + CCTX * CIN) {
        int j = i - DCH * CIN;
        oc[j] = (short)f2bf(wc[j]);
    }
}

// ---------------- conv3x3+relu, 32x32x16 MFMA version -------------------------
// Block = 128 threads = 2 waves; tile 128sp x 64co; wave tile 64sp x 64co.
// ci staged 16 at a time (32 kc steps). LDS row stride XP=24 shorts (48 B):
// start-bank 12*row mod 32 covers all multiples of 4 evenly -> conflict floor.
// tile id: [layer][img][co_blk (8)][sp_blk (6)]; layer B iff tile >= TPL.
__global__ __launch_bounds__(128, 2) void conv3w_k(
    const short* __restrict__ xt,
    const short* __restrict__ wA, short* __restrict__ outA,
    const short* __restrict__ wB, short* __restrict__ outB,
    int ntiles)
{
    __shared__ short Xs[WROWS * XP];      // 11,136 B
    __shared__ short Wsh[9 * 64 * XP];    // 27,648 B
    const int tile = blockIdx.x;
    if (tile >= ntiles) return;

    const int tid = threadIdx.x;
    const int lane = tid & 63, wave = tid >> 6;
    const int l31 = lane & 31, lh = lane >> 5;
    const int koff = lh * 8;              // k-offset (shorts) within 16-ci chunk

    int t = tile;
    const int layer = (t >= TPL);
    if (layer) t -= TPL;
    const int n = t / 48;
    const int r48 = t - n * 48;
    const int cb = r48 / 6;
    const int sb = r48 - cb * 6;
    const short* __restrict__ wth = layer ? wB : wA;
    short* __restrict__ xout = layer ? outB : outA;

    const int s0 = sb * 128;
    const int co0 = cb * 64;
    const int base = spad_of(s0) - 47;
    const short* xb = xt + ((size_t)n * XSTR + base) * 512;

    // per-lane A rows (spatial), padded-row space, window-relative
    int sloc[2];
#pragma unroll
    for (int mf = 0; mf < 2; ++mf)
        sloc[mf] = spad_of(s0 + wave * 64 + mf * 32 + l31) - base;

    const f32x16 z16 = {0.f,0.f,0.f,0.f,0.f,0.f,0.f,0.f,
                        0.f,0.f,0.f,0.f,0.f,0.f,0.f,0.f};
    f32x16 acc[2][2];
#pragma unroll
    for (int mf = 0; mf < 2; ++mf)
#pragma unroll
        for (int nf = 0; nf < 2; ++nf) acc[mf][nf] = z16;

    for (int kc = 0; kc < 32; ++kc) {
        __syncthreads();
        // stage X window: 232 rows x 2 halves (16 B each) = 464 tasks
#pragma unroll
        for (int it = 0; it < 4; ++it) {
            int q = it * 128 + tid;
            if (q < WROWS * 2) {
                int row = q >> 1, hh = q & 1;
                *(bf16x8*)&Xs[row * XP + hh * 8] =
                    *(const bf16x8*)(xb + (size_t)row * 512 + kc * 16 + hh * 8);
            }
        }
        // stage W: 9 taps x 64 co x 2 halves = 1152 tasks (exactly 9 iters)
#pragma unroll
        for (int it = 0; it < 9; ++it) {
            int q = it * 128 + tid;
            int tco = q >> 1, hh = q & 1;
            *(bf16x8*)&Wsh[tco * XP + hh * 8] =
                *(const bf16x8*)(wth + ((size_t)(tco >> 6) * CIN + co0 + (tco & 63)) * CIN
                                 + kc * 16 + hh * 8);
        }
        __syncthreads();
        constexpr int OFF[9] = {-47, -46, -45, -1, 0, 1, 45, 46, 47};
#pragma unroll
        for (int t9 = 0; t9 < 9; ++t9) {
            const int off = OFF[t9];
            bf16x8 a0 = *(const bf16x8*)&Xs[(sloc[0] + off) * XP + koff];
            bf16x8 a1 = *(const bf16x8*)&Xs[(sloc[1] + off) * XP + koff];
            bf16x8 b0 = *(const bf16x8*)&Wsh[(t9 * 64 + l31) * XP + koff];
            bf16x8 b1 = *(const bf16x8*)&Wsh[(t9 * 64 + 32 + l31) * XP + koff];
            acc[0][0] = __builtin_amdgcn_mfma_f32_32x32x16_bf16(a0, b0, acc[0][0], 0, 0, 0);
            acc[0][1] = __builtin_amdgcn_mfma_f32_32x32x16_bf16(a0, b1, acc[0][1], 0, 0, 0);
            acc[1][0] = __builtin_amdgcn_mfma_f32_32x32x16_bf16(a1, b0, acc[1][0], 0, 0, 0);
            acc[1][1] = __builtin_amdgcn_mfma_f32_32x32x16_bf16(a1, b1, acc[1][1], 0, 0, 0);
        }
    }
    // epilogue: C col = l31 (co), row = (r&3) + 8*(r>>2) + 4*lh (spatial)
#pragma unroll
    for (int mf = 0; mf < 2; ++mf) {
        const int spb = wave * 64 + mf * 32 + 4 * lh;
#pragma unroll
        for (int r = 0; r < 16; ++r) {
            const int sg = s0 + spb + (r & 3) + 8 * (r >> 2);
            if (sg < SP_) {
                const size_t ro = ((size_t)n * XSTR + spad_of(sg)) * 512 + co0 + l31;
#pragma unroll
                for (int nf = 0; nf < 2; ++nf)
                    xout[ro + nf * 32] = (short)f2bf(fmaxf(acc[mf][nf][r], 0.f));
            }
        }
    }
}

// ---------------- 1x1 conv as GEMM: xt bf16 -> fp32 [n][s][NCO] ---------------
template <int NCO>
__global__ __launch_bounds__(256, 2) void gemm1x1_k(
    const short* __restrict__ xtin, const short* __restrict__ wb,
    const float* __restrict__ bias, float* __restrict__ outT)
{
    constexpr int NST = NCO / 16;
    __shared__ short Wb[NCO * CIP];
    const int tid = threadIdx.x;
    const int s0 = blockIdx.x * 128, n = blockIdx.z;
    const int lane = tid & 63, wave = tid >> 6;
    const int kg = lane >> 4, lrow = lane & 15;
    const int swave = s0 + wave * 32;

    int arow[2];
#pragma unroll
    for (int ms = 0; ms < 2; ++ms)
        arow[ms] = spad_of(swave + ms * 16 + lrow);

    const f32x4 zero4 = {0.f, 0.f, 0.f, 0.f};
    f32x4 acc[2][NST];
#pragma unroll
    for (int ms = 0; ms < 2; ++ms)
#pragma unroll
        for (int ns = 0; ns < NST; ++ns) acc[ms][ns] = zero4;

    const short* xb = xtin + (size_t)n * XSTR * 512;

    for (int kc = 0; kc < 16; ++kc) {
        __syncthreads();
#pragma unroll
        for (int it = 0; it < 2; ++it) {
            int q = it * 256 + tid;
            if (q < NCO * 4) {
                int co = q >> 2, p = q & 3;
                *(bf16x8*)&Wb[co * CIP + p * 8] =
                    *(const bf16x8*)(wb + (size_t)co * CIN + kc * 32 + p * 8);
            }
        }
        __syncthreads();
        bf16x8 a[2];
#pragma unroll
        for (int ms = 0; ms < 2; ++ms)
            a[ms] = *(const bf16x8*)(xb + (size_t)arow[ms] * 512 + kc * 32 + kg * 8);
#pragma unroll
        for (int ns = 0; ns < NST; ++ns) {
            int co = ns * 16 + lrow;
            bf16x8 b = *(const bf16x8*)&Wb[co * CIP + kg * 8];
#pragma unroll
            for (int ms = 0; ms < 2; ++ms)
                acc[ms][ns] = __builtin_amdgcn_mfma_f32_16x16x32_bf16(
                    a[ms], b, acc[ms][ns], 0, 0, 0);
        }
    }
#pragma unroll
    for (int ms = 0; ms < 2; ++ms)
#pragma unroll
        for (int ns = 0; ns < NST; ++ns)
#pragma unroll
            for (int r = 0; r < 4; ++r) {
                int sg = swave + ms * 16 + kg * 4 + r;
                if (sg < SP_) {
                    int co = ns * 16 + lrow;
                    outT[((size_t)n * SP_ + sg) * NCO + co] = acc[ms][ns][r] + bias[co];
                }
            }
}

// ---------------- softmax over d, layout [n][s][112] (d contiguous) ----------
__global__ __launch_bounds__(256) void softmax2_k(
    const float* __restrict__ lg, float* __restrict__ pr)
{
    const int p = blockIdx.x * 4 + (threadIdx.x >> 6);
    if (p >= NIMG * SP_) return;
    const int lane = threadIdx.x & 63;
    const float* lp = lg + (size_t)p * DCH;
    float v0 = lp[lane];
    float v1 = (lane < DCH - 64) ? lp[64 + lane] : -1e30f;
    float m = fmaxf(v0, v1);
#pragma unroll
    for (int o = 32; o; o >>= 1) m = fmaxf(m, __shfl_xor(m, o));
    float e0 = __expf(v0 - m);
    float e1 = (lane < DCH - 64) ? __expf(v1 - m) : 0.f;
    float s = e0 + e1;
#pragma unroll
    for (int o = 32; o; o >>= 1) s += __shfl_xor(s, o);
    const float inv = 1.f / s;
    float* pp = pr + (size_t)p * DCH;
    pp[lane] = e0 * inv;
    if (lane < DCH - 64) pp[64 + lane] = e1 * inv;
}

// ---------------- per-camera geometry constants (fp64, closed-form) ----------
__device__ __forceinline__ void inv4(const double* M, double* inv) {
    inv[0]  =  M[5]*M[10]*M[15] - M[5]*M[11]*M[14] - M[9]*M[6]*M[15] + M[9]*M[7]*M[14] + M[13]*M[6]*M[11] - M[13]*M[7]*M[10];
    inv[4]  = -M[4]*M[10]*M[15] + M[4]*M[11]*M[14] + M[8]*M[6]*M[15] - M[8]*M[7]*M[14] - M[12]*M[6]*M[11] + M[12]*M[7]*M[10];
    inv[8]  =  M[4]*M[9]*M[15]  - M[4]*M[11]*M[13] - M[8]*M[5]*M[15] + M[8]*M[7]*M[13] + M[12]*M[5]*M[11] - M[12]*M[7]*M[9];
    inv[12] = -M[4]*M[9]*M[14]  + M[4]*M[10]*M[13] + M[8]*M[5]*M[14] - M[8]*M[6]*M[13] - M[12]*M[5]*M[10] + M[12]*M[6]*M[9];
    inv[1]  = -M[1]*M[10]*M[15] + M[1]*M[11]*M[14] + M[9]*M[2]*M[15] - M[9]*M[3]*M[14] - M[13]*M[2]*M[11] + M[13]*M[3]*M[10];
    inv[5]  =  M[0]*M[10]*M[15] - M[0]*M[11]*M[14] - M[8]*M[2]*M[15] + M[8]*M[3]*M[14] + M[12]*M[2]*M[11] - M[12]*M[3]*M[10];
    inv[9]  = -M[0]*M[9]*M[15]  + M[0]*M[11]*M[13] + M[8]*M[1]*M[15] - M[8]*M[3]*M[13] - M[12]*M[1]*M[11] + M[12]*M[3]*M[9];
    inv[13] =  M[0]*M[9]*M[14]  - M[0]*M[10]*M[13] - M[8]*M[1]*M[14] + M[8]*M[2]*M[13] + M[12]*M[1]*M[10] - M[12]*M[2]*M[9];
    inv[2]  =  M[1]*M[6]*M[15]  - M[1]*M[7]*M[14]  - M[5]*M[2]*M[15] + M[5]*M[3]*M[14] + M[13]*M[2]*M[7]  - M[13]*M[3]*M[6];
    inv[6]  = -M[0]*M[6]*M[15]  + M[0]*M[7]*M[14]  + M[4]*M[2]*M[15] - M[4]*M[3]*M[14] - M[12]*M[2]*M[7]  + M[12]*M[3]*M[6];
    inv[10] =  M[0]*M[5]*M[15]  - M[0]*M[7]*M[13]  - M[4]*M[1]*M[15] + M[4]*M[3]*M[13] + M[12]*M[1]*M[7]  - M[12]*M[3]*M[5];
    inv[14] = -M[0]*M[5]*M[14]  + M[0]*M[6]*M[13]  + M[4]*M[1]*M[14] - M[4]*M[2]*M[13] - M[12]*M[1]*M[6]  + M[12]*M[2]*M[5];
    inv[3]  = -M[1]*M[6]*M[11]  + M[1]*M[7]*M[10]  + M[5]*M[2]*M[11] - M[5]*M[3]*M[10] - M[9]*M[2]*M[7]   + M[9]*M[3]*M[6];
    inv[7]  =  M[0]*M[6]*M[11]  - M[0]*M[7]*M[10]  - M[4]*M[2]*M[11] + M[4]*M[3]*M[10] + M[8]*M[2]*M[7]   - M[8]*M[3]*M[6];
    inv[11] = -M[0]*M[5]*M[11]  + M[0]*M[7]*M[9]   + M[4]*M[1]*M[11] - M[4]*M[3]*M[9]  - M[8]*M[1]*M[7]   + M[8]*M[3]*M[5];
    inv[15] =  M[0]*M[5]*M[10]  - M[0]*M[6]*M[9]   - M[4]*M[1]*M[10] + M[4]*M[2]*M[9]  + M[8]*M[1]*M[6]   - M[8]*M[2]*M[5];
    double det = M[0]*inv[0] + M[1]*inv[4] + M[2]*inv[8] + M[3]*inv[12];
    double id = 1.0 / det;
#pragma unroll
    for (int i = 0; i < 16; ++i) inv[i] *= id;
}

__global__ void geom_setup_k(const float* __restrict__ s2e, const float* __restrict__ intrin,
                             const float* __restrict__ ida, const float* __restrict__ bda,
                             double* __restrict__ gc)
{
    const int n = threadIdx.x;
    if (n >= NIMG) return;
    double M[16], Iv[16];
#pragma unroll
    for (int i = 0; i < 16; ++i) M[i] = (double)ida[n * 16 + i];
    inv4(M, Iv);
    double R[3][3], tv[3];
#pragma unroll
    for (int r = 0; r < 3; ++r) {
#pragma unroll
        for (int c = 0; c < 3; ++c) R[r][c] = Iv[r * 4 + c];
        tv[r] = Iv[r * 4 + 3];
    }
    double K[3][3];
#pragma unroll
    for (int r = 0; r < 3; ++r)
#pragma unroll
        for (int c = 0; c < 3; ++c) K[r][c] = (double)intrin[n * 16 + r * 4 + c];
    double det = K[0][0] * (K[1][1] * K[2][2] - K[1][2] * K[2][1])
               - K[0][1] * (K[1][0] * K[2][2] - K[1][2] * K[2][0])
               + K[0][2] * (K[1][0] * K[2][1] - K[1][1] * K[2][0]);
    double id = 1.0 / det;
    double Ki[3][3];
    Ki[0][0] = (K[1][1] * K[2][2] - K[1][2] * K[2][1]) * id;
    Ki[0][1] = (K[0][2] * K[2][1] - K[0][1] * K[2][2]) * id;
    Ki[0][2] = (K[0][1] * K[1][2] - K[0][2] * K[1][1]) * id;
    Ki[1][0] = (K[1][2] * K[2][0] - K[1][0] * K[2][2]) * id;
    Ki[1][1] = (K[0][0] * K[2][2] - K[0][2] * K[2][0]) * id;
    Ki[1][2] = (K[0][2] * K[1][0] - K[0][0] * K[1][2]) * id;
    Ki[2][0] = (K[1][0] * K[2][1] - K[1][1] * K[2][0]) * id;
    Ki[2][1] = (K[0][1] * K[2][0] - K[0][0] * K[2][1]) * id;
    Ki[2][2] = (K[0][0] * K[1][1] - K[0][1] * K[1][0]) * id;
    double A[3][3], bv[3];
#pragma unroll
    for (int r = 0; r < 3; ++r) {
#pragma unroll
        for (int c = 0; c < 3; ++c)
            A[r][c] = Ki[r][0] * R[0][c] + Ki[r][1] * R[1][c] + Ki[r][2] * R[2][c];
        bv[r] = Ki[r][0] * tv[0] + Ki[r][1] * tv[1] + Ki[r][2] * tv[2];
    }
    double* g = gc + n * 24;
#pragma unroll
    for (int r = 0; r < 3; ++r)
#pragma unroll
        for (int c = 0; c < 3; ++c) g[r * 3 + c] = A[r][c];
#pragma unroll
    for (int r = 0; r < 3; ++r) g[9 + r] = bv[r];
#pragma unroll
    for (int r = 0; r < 3; ++r)
#pragma unroll
        for (int c = 0; c < 4; ++c) {
            double acc = 0.0;
#pragma unroll
            for (int k = 0; k < 4; ++k)
                acc += (double)bda[r * 4 + k] * (double)s2e[n * 16 + k * 4 + c];
            g[12 + r * 4 + c] = acc;
        }
}

// ---------------- per-point voxel index + histogram (fused) ------------------
__global__ __launch_bounds__(256) void point_voxel_k(
    const double* __restrict__ gc, int* __restrict__ vidx, int* __restrict__ cnt)
{
    const int i = blockIdx.x * 256 + threadIdx.x;
    if (i >= NPTS) return;
    const int n = i / (DCH * SP_);
    int r = i - n * (DCH * SP_);
    const int di = r / SP_;
    const int s = r - di * SP_;
    const int h = s / FW_, w = s - h * FW_;
    const double* g = gc + n * 24;
    const double u  = (double)(float)((double)w * (703.0 / 43.0));
    const double v  = (double)(float)((double)h * 17.0);
    const double dd = (double)(float)(2.0 + (double)di * (56.0 / 111.0));
    const double rx = g[0] * u + g[1] * v + g[2] + g[9];
    const double ry = g[3] * u + g[4] * v + g[5] + g[10];
    const double rz = g[6] * u + g[7] * v + g[8] + g[11];
    const double px = rx * dd, py = ry * dd, pz = rz * dd;
    const double ex = g[12] * px + g[13] * py + g[14] * pz + g[15];
    const double ey = g[16] * px + g[17] * py + g[18] * pz + g[19];
    const double ez = g[20] * px + g[21] * py + g[22] * pz + g[23];
    const double vs_xy = 0.8, vs_z = 8.0;
    const double offx = (double)(float)(-51.2 + 0.4) - vs_xy * 0.5;
    const double offz = (double)(float)(-5.0 + 4.0) - vs_z * 0.5;
    const int gx = (int)((ex - offx) / vs_xy);
    const int gy = (int)((ey - offx) / vs_xy);
    const int gz = (int)((ez - offz) / vs_z);
    const bool ok = (gx >= 0 && gx < NXY && gy >= 0 && gy < NXY && gz == 0);
    const int vv = ok ? (gy * NXY + gx) : -1;
    vidx[i] = vv;
    if (vv >= 0) atomicAdd(&cnt[vv], 1);
}

// off has NVOX+1 entries; off[NVOX] = total valid points
__global__ void prefix_k(const int* __restrict__ cnt, int* __restrict__ off,
                         int* __restrict__ cur) {
    __shared__ int part[256];
    const int t = threadIdx.x;
    int s = 0;
    for (int j = 0; j < 64; ++j) s += cnt[t * 64 + j];
    part[t] = s;
    __syncthreads();
    if (t == 0) {
        int run = 0;
        for (int k = 0; k < 256; ++k) { int v = part[k]; part[k] = run; run += v; }
    }
    __syncthreads();
    int base = part[t];
    for (int j = 0; j < 64; ++j) {
        off[t * 64 + j] = base;
        cur[t * 64 + j] = base;
        base += cnt[t * 64 + j];
    }
    if (t == 255) off[NVOX] = base;
}

// fill packed entries: key = (v<<13) | (n*SP_+s), prob bits; prob [n][s][112]
__global__ void fill_k(const int* __restrict__ vidx, const float* __restrict__ prob,
                       int* __restrict__ cur, int2* __restrict__ pk) {
    int i = blockIdx.x * 256 + threadIdx.x;
    if (i >= NPTS) return;
    int v = vidx[i];
    if (v < 0) return;
    const int n = i / (DCH * SP_);
    int r = i - n * (DCH * SP_);
    const int di = r / SP_;
    const int s = r - di * SP_;
    int pos = atomicAdd(&cur[v], 1);
    pk[pos] = make_int2((v << 13) | (n * SP_ + s),
                        __float_as_int(prob[((size_t)n * SP_ + s) * DCH + di]));
}

// ---------------- gather: chunk-per-wave segmented reduction ------------------
__global__ __launch_bounds__(256) void gather2_k(
    const int2* __restrict__ pk, const int* __restrict__ off,
    const float* __restrict__ ctxT, float* __restrict__ accT)
{
    const int gtid = blockIdx.x * 256 + threadIdx.x;
    const int wid = gtid >> 6;
    const int lane = threadIdx.x & 63;
    const int total = off[NVOX];
    const int lo = wid * CHUNK;
    if (lo >= total) return;
    const int hi = min(lo + CHUNK, total);
    float a0 = 0.f, a1 = 0.f;
    int2 e = pk[lo];
    for (int k = lo; k < hi; ++k) {
        const int2 en = (k + 1 < hi) ? pk[k + 1] : make_int2(-1, 0);
        const float p = __int_as_float(e.y);
        const int ns = e.x & 8191;
        const float* cb = ctxT + (size_t)ns * CCTX;
        a0 = fmaf(p, cb[lane], a0);
        if (lane < CCTX - 64) a1 = fmaf(p, cb[64 + lane], a1);
        if ((en.x >> 13) != (e.x >> 13)) {         // wave-uniform flush
            float* ab = accT + (size_t)(e.x >> 13) * CCTX;
            atomicAdd(ab + lane, a0);
            if (lane < CCTX - 64) atomicAdd(ab + 64 + lane, a1);
            a0 = a1 = 0.f;
        }
        e = en;
    }
}

// ---------------- transpose accT [v][c] -> out [c][v] ------------------------
__global__ void transpose_out_k(const float* __restrict__ accT, float* __restrict__ out) {
    const int idx = blockIdx.x * 256 + threadIdx.x;
    if (idx >= CCTX * NVOX) return;
    const int c = idx >> 14;
    const int v = idx & 16383;
    out[idx] = accT[(size_t)v * CCTX + c];
}

// ---------------- workspace layout (float offsets) ---------------------------
#define O_WHIA  512           // bf16 conv weights A [9][512][512]: 1,179,648
#define O_WHIB  1180160       // bf16 conv weights B: 1,179,648
#define O_XT0   2359808       // 1,474,560
#define O_XT1   3834368       // 1,474,560
#define O_XT2   5308928       // 1,474,560
#define O_WD2B  6783488       // 28,672 (bf16 112x512)
#define O_WC2B  6812160       // 20,480 (bf16 80x512)
#define O_DLG   6832640       // 473,088  [n][s][112]
#define O_DPR   7305728       // 473,088
#define O_CTX   7778816       // 337,920  [n][s][80]
#define O_PK    8116736       // 946,176 (int2 x 473,088)
#define O_VIX   9062912       // 473,088
#define O_CNT   9536000       // 16,384
#define O_OFF   9552384       // 16,400
#define O_CUR   9568784       // 16,384
#define O_ACC   9585168       // 1,310,720
// end: 10,895,888 floats = 43.6 MB

extern "C" void kernel_launch(void* const* d_in, const int* in_sizes, int n_in,
                              void* d_out, int out_size, void* d_ws, size_t ws_size,
                              hipStream_t stream)
{
    const float* src  = (const float*)d_in[0];
    const float* w_s1 = (const float*)d_in[1];
    const float* w_s2 = (const float*)d_in[2];
    const float* w_d1 = (const float*)d_in[3];
    const float* w_d2 = (const float*)d_in[4];
    const float* b_d  = (const float*)d_in[5];
    const float* w_c1 = (const float*)d_in[6];
    const float* w_c2 = (const float*)d_in[7];
    const float* b_c  = (const float*)d_in[8];
    const float* s2e  = (const float*)d_in[9];
    const float* intr = (const float*)d_in[10];
    const float* ida  = (const float*)d_in[11];
    const float* bda  = (const float*)d_in[12];

    double* gc = (double*)d_ws;
    float* ws   = (float*)d_ws;
    short* whiA = (short*)(ws + O_WHIA);
    short* whiB = (short*)(ws + O_WHIB);
    short* xt0  = (short*)(ws + O_XT0);
    short* xt1  = (short*)(ws + O_XT1);
    short* xt2  = (short*)(ws + O_XT2);
    short* wd2b = (short*)(ws + O_WD2B);
    short* wc2b = (short*)(ws + O_WC2B);
    float* dlog = ws + O_DLG;
    float* dprb = ws + O_DPR;
    float* ctxT = ws + O_CTX;
    int2*  pk   = (int2*)(ws + O_PK);
    int* vidx   = (int*)(ws + O_VIX);
    int* cnt    = (int*)(ws + O_CNT);
    int* offs   = (int*)(ws + O_OFF);
    int* cur    = (int*)(ws + O_CUR);
    float* accT = ws + O_ACC;
    float* out  = (float*)d_out;

    // zero xt0+xt1 (contiguous; provides pad borders). xt2 rows fully written
    // by d1 before being read -> no zeroing needed.
    zero_k<<<(2949120 / 4 + 255) / 256, 256, 0, stream>>>((float4*)xt0, 2949120 / 4);

    geom_setup_k<<<1, 64, 0, stream>>>(s2e, intr, ida, bda, gc);
    src_to_xt_k<<<(NIMG * SP_ * CIN + 255) / 256, 256, 0, stream>>>(src, xt0);

    // s1: xt0 -> xt1
    wsplit_k<<<(CIN * CIN) / 256, 256, 0, stream>>>(w_s1, whiA);
    conv3w_k<<<TPL, 128, 0, stream>>>(xt0, whiA, xt1, whiA, xt1, TPL);
    // s2: xt1 -> xt0
    wsplit_k<<<(CIN * CIN) / 256, 256, 0, stream>>>(w_s2, whiA);
    conv3w_k<<<TPL, 128, 0, stream>>>(xt1, whiA, xt0, whiA, xt0, TPL);
    // d1 + c1 fused: xt0 -> xt2 (depth branch), xt0 -> xt1 (context branch)
    wsplit_dual_k<<<(2 * CIN * CIN) / 256, 256, 0, stream>>>(w_d1, whiA, w_c1, whiB);
    conv3w_k<<<2 * TPL, 128, 0, stream>>>(xt0, whiA, xt2, whiB, xt1, 2 * TPL);

    // 1x1 weights (both) in one dispatch
    wsplit1_dual_k<<<((DCH + CCTX) * CIN + 255) / 256, 256, 0, stream>>>(w_d2, wd2b, w_c2, wc2b);
    // d2 gemm: xt2 -> dlog [n][s][112]; softmax -> dprb
    gemm1x1_k<DCH><<<dim3(6, 1, NIMG), 256, 0, stream>>>(xt2, wd2b, b_d, dlog);
    softmax2_k<<<(NIMG * SP_ + 3) / 4, 256, 0, stream>>>(dlog, dprb);
    // c2 gemm: xt1 -> ctxT [n][s][80]
    gemm1x1_k<CCTX><<<dim3(6, 1, NIMG), 256, 0, stream>>>(xt1, wc2b, b_c, ctxT);

    // binning
    zero_k<<<(NVOX / 4 + 255) / 256, 256, 0, stream>>>((float4*)cnt, NVOX / 4);
    point_voxel_k<<<(NPTS + 255) / 256, 256, 0, stream>>>(gc, vidx, cnt);
    prefix_k<<<1, 256, 0, stream>>>(cnt, offs, cur);
    fill_k<<<(NPTS + 255) / 256, 256, 0, stream>>>(vidx, dprb, cur, pk);

    // segmented-reduction gather
    zero_k<<<(1310720 / 4 + 255) / 256, 256, 0, stream>>>((float4*)accT, 1310720 / 4);
    {
        const int waves = (NPTS + CHUNK - 1) / CHUNK;
        const int blocks = (waves + 3) / 4;
        gather2_k<<<blocks, 256, 0, stream>>>(pk, offs, ctxT, accT);
    }
    transpose_out_k<<<(CCTX * NVOX + 255) / 256, 256, 0, stream>>>(accT, out);

    (void)in_sizes; (void)n_in; (void)out_size; (void)ws_size;
}